// Round 1
// baseline (26.716 us; speedup 1.0000x reference)
//
#include <hip/hip_runtime.h>
#include <math.h>

#define DT 0.2f
#define LEN_HIST 16

__global__ __launch_bounds__(256) void kalman_cv_kernel(
    const float* __restrict__ hist,
    const float* __restrict__ vsx_p, const float* __restrict__ vsy_p,
    const float* __restrict__ asx_p, const float* __restrict__ asy_p,
    const float* __restrict__ GR_p,  const float* __restrict__ coefG_p,
    float* __restrict__ out, int B, int len_pred)
{
    int b = blockIdx.x * blockDim.x + threadIdx.x;
    if (b >= B) return;

    // ---- constants / process & measurement noise ----
    const float Gv0 = DT * DT * 0.5f, Gv1 = DT, Gv2 = DT * DT * 0.5f, Gv3 = DT;
    float ax2 = asx_p[0] * asx_p[0];
    float ay2 = asy_p[0] * asy_p[0];
    float g[4];
    g[0] = Gv0 * tanhf(coefG_p[0]);
    g[1] = Gv1 * tanhf(coefG_p[1]);
    g[2] = Gv2 * tanhf(coefG_p[2]);
    g[3] = Gv3 * tanhf(coefG_p[3]);
    float Q[4][4];
    #pragma unroll
    for (int i = 0; i < 4; ++i) {
        #pragma unroll
        for (int j = 0; j < 4; ++j) {
            float s = (i < 2) ? ((j < 2) ? ax2 : 1.0f)
                              : ((j < 2) ? 1.0f : ay2);
            Q[i][j] = g[i] * g[j] * s;
        }
    }
    float GR0 = GR_p[0], GR1 = GR_p[1];
    float R00 = GR0 * GR0, R01 = GR0 * GR1, R10 = GR1 * GR0, R11 = GR1 * GR1;
    float vsx2 = vsx_p[0] * vsx_p[0];
    float vsy2 = vsy_p[0] * vsy_p[0];

    // ---- load all measurements (coalesced float2) ----
    float2 z[LEN_HIST];
    #pragma unroll
    for (int t = 0; t < LEN_HIST; ++t)
        z[t] = *reinterpret_cast<const float2*>(hist + ((size_t)t * B + b) * 2);

    // ---- init state & covariance ----
    float X0 = z[0].x;
    float X1 = (z[1].x - z[0].x) / DT;
    float X2 = z[0].y;
    float X3 = (z[1].y - z[0].y) / DT;

    float P[4][4] = {};
    P[0][0] = R00; P[1][1] = vsx2; P[2][2] = R11; P[3][3] = vsy2;

    // ---- filter: 15 measurement updates ----
    #pragma unroll
    for (int t = 1; t < LEN_HIST; ++t) {
        // predict: X = F X
        X0 += DT * X1;
        X2 += DT * X3;
        // P = F P F^T + Q  (F banded: row0 += DT*row1, row2 += DT*row3; same on cols)
        float T[4][4];
        #pragma unroll
        for (int j = 0; j < 4; ++j) {
            T[0][j] = P[0][j] + DT * P[1][j];
            T[1][j] = P[1][j];
            T[2][j] = P[2][j] + DT * P[3][j];
            T[3][j] = P[3][j];
        }
        #pragma unroll
        for (int i = 0; i < 4; ++i) {
            P[i][0] = T[i][0] + DT * T[i][1] + Q[i][0];
            P[i][1] = T[i][1]               + Q[i][1];
            P[i][2] = T[i][2] + DT * T[i][3] + Q[i][2];
            P[i][3] = T[i][3]               + Q[i][3];
        }

        // innovation
        float y0 = z[t].x - X0;
        float y1 = z[t].y - X2;
        float S00 = P[0][0] + R00, S01 = P[0][2] + R01;
        float S10 = P[2][0] + R10, S11 = P[2][2] + R11;
        float inv = 1.0f / (S00 * S11 - S01 * S10);
        float Si00 =  S11 * inv, Si01 = -S01 * inv;
        float Si10 = -S10 * inv, Si11 =  S00 * inv;

        // K = P H^T S^{-1}  (uses cols 0,2 of P)
        float K[4][2];
        #pragma unroll
        for (int i = 0; i < 4; ++i) {
            K[i][0] = P[i][0] * Si00 + P[i][2] * Si10;
            K[i][1] = P[i][0] * Si01 + P[i][2] * Si11;
        }

        X0 += K[0][0] * y0 + K[0][1] * y1;
        X1 += K[1][0] * y0 + K[1][1] * y1;
        X2 += K[2][0] * y0 + K[2][1] * y1;
        X3 += K[3][0] * y0 + K[3][1] * y1;

        // P = (I-KH) P (I-KH)^T + K R K^T ; K R K^T = outer(w,w), w = K @ GR
        float U[4][4];
        #pragma unroll
        for (int i = 0; i < 4; ++i) {
            #pragma unroll
            for (int j = 0; j < 4; ++j)
                U[i][j] = P[i][j] - K[i][0] * P[0][j] - K[i][1] * P[2][j];
        }
        float w[4];
        #pragma unroll
        for (int i = 0; i < 4; ++i)
            w[i] = K[i][0] * GR0 + K[i][1] * GR1;
        #pragma unroll
        for (int i = 0; i < 4; ++i) {
            #pragma unroll
            for (int j = 0; j < 4; ++j)
                P[i][j] = U[i][j] - U[i][0] * K[j][0] - U[i][2] * K[j][1] + w[i] * w[j];
        }
    }

    // ---- prediction: len_pred steps, emit (mu_x, mu_y, sx, sy, rho) ----
    size_t ob = (size_t)b * 5;
    for (int l = 0; l < len_pred; ++l) {
        X0 += DT * X1;
        X2 += DT * X3;
        float T[4][4];
        #pragma unroll
        for (int j = 0; j < 4; ++j) {
            T[0][j] = P[0][j] + DT * P[1][j];
            T[1][j] = P[1][j];
            T[2][j] = P[2][j] + DT * P[3][j];
            T[3][j] = P[3][j];
        }
        #pragma unroll
        for (int i = 0; i < 4; ++i) {
            P[i][0] = T[i][0] + DT * T[i][1] + Q[i][0];
            P[i][1] = T[i][1]               + Q[i][1];
            P[i][2] = T[i][2] + DT * T[i][3] + Q[i][2];
            P[i][3] = T[i][3]               + Q[i][3];
        }
        float sx = sqrtf(P[0][0]);
        float sy = sqrtf(P[2][2]);
        float rho = (P[0][2] + P[2][0]) / (2.0f * sx * sy);
        float* o = out + (size_t)l * B * 5 + ob;
        o[0] = X0;
        o[1] = X2;
        o[2] = sx;
        o[3] = sy;
        o[4] = rho;
    }
}

extern "C" void kernel_launch(void* const* d_in, const int* in_sizes, int n_in,
                              void* d_out, int out_size, void* d_ws, size_t ws_size,
                              hipStream_t stream) {
    const float* hist  = (const float*)d_in[0];
    const float* vsx   = (const float*)d_in[1];
    const float* vsy   = (const float*)d_in[2];
    const float* asx   = (const float*)d_in[3];
    const float* asy   = (const float*)d_in[4];
    const float* GR    = (const float*)d_in[5];
    const float* coefG = (const float*)d_in[6];
    float* out = (float*)d_out;

    int B = in_sizes[0] / (LEN_HIST * 2);
    int len_pred = out_size / (B * 5);

    int block = 256;
    int grid = (B + block - 1) / block;
    kalman_cv_kernel<<<grid, block, 0, stream>>>(hist, vsx, vsy, asx, asy, GR, coefG,
                                                 out, B, len_pred);
}